// Round 1
// baseline (552.138 us; speedup 1.0000x reference)
//
#include <hip/hip_runtime.h>

typedef __attribute__((ext_vector_type(4))) float f4;
typedef __attribute__((ext_vector_type(4))) float f32x4;
typedef __attribute__((ext_vector_type(8))) short short8;
typedef __attribute__((ext_vector_type(4))) short short4v;
typedef __attribute__((ext_vector_type(4))) unsigned int uint4v;

#define S_  4096
#define NB_ 16
#define SLOPE_SCALE 0.838719677419355f

__device__ __forceinline__ float slope_for_head(int h) {
    return exp2f(-(float)(h + 1) * 0.125f) * SLOPE_SCALE;
}

// fp32 -> bf16 round-to-nearest-even
__device__ __forceinline__ short f2bf(float f) {
    unsigned u = __float_as_uint(f);
    u += 0x7FFFu + ((u >> 16) & 1u);
    return (short)(u >> 16);
}

// ---------------------------------------------------------------------------
// Phase 1: per-(bh, block j): KVT[e][d] = sum_n v[n][e]*k_decay[n]*k[n][d]
// (fp32, stored e-major = transposed kv, which is what phase 3's MFMA wants)
// Also writes masked V^T as bf16: vt[(bh*64+e)*S + n]
// ---------------------------------------------------------------------------
__global__ __launch_bounds__(256, 4) void phase1_kvblocks(
    const float* __restrict__ k, const float* __restrict__ v,
    const int* __restrict__ mask, float* __restrict__ kvt,
    short* __restrict__ vt)
{
    __shared__ float ks[64][68];
    __shared__ float vs[64][68];
    const int j  = blockIdx.x;   // 0..15
    const int bh = blockIdx.y;   // 0..127
    const int b  = bh >> 6;
    const int h  = bh & 63;
    const int t  = threadIdx.x;
    const float slope = slope_for_head(h);
    const int e  = t >> 2;          // 0..63
    const int dg = (t & 3) << 4;    // 0,16,32,48

    const f32x4 zf = {0.f, 0.f, 0.f, 0.f};
    f4 acc[4];
    acc[0] = zf; acc[1] = zf; acc[2] = zf; acc[3] = zf;

    const long long tilebase = ((long long)bh * S_ + j * 256) * 64;

    for (int c = 0; c < 4; ++c) {
        // stage 64 rows of k and (masked) v
        for (int i = 0; i < 4; ++i) {
            int fi  = t + i * 256;       // 0..1023
            int row = fi >> 4;           // 0..63
            int col = (fi & 15) << 2;    // 0..60
            long long g = tilebase + (long long)(c * 64 + row) * 64 + col;
            *(f4*)&ks[row][col] = *(const f4*)(k + g);
            f4 vv = *(const f4*)(v + g);
            float mv = (float)mask[b * S_ + j * 256 + c * 64 + row];
            vv *= mv;
            *(f4*)&vs[row][col] = vv;
        }
        __syncthreads();

        for (int n = 0; n < 64; ++n) {
            float kd = __expf(-slope * (float)(255 - (c * 64 + n)));
            float a  = vs[n][e] * kd;
            const f4* krow = (const f4*)&ks[n][dg];
            acc[0] += a * krow[0];
            acc[1] += a * krow[1];
            acc[2] += a * krow[2];
            acc[3] += a * krow[3];
        }

        // write V^T bf16: this thread covers (e, 16 n's)
        {
            int nb = (t & 3) << 4;
            unsigned w[8];
            for (int i = 0; i < 8; ++i) {
                unsigned lo = (unsigned short)f2bf(vs[nb + 2 * i][e]);
                unsigned hi = (unsigned short)f2bf(vs[nb + 2 * i + 1][e]);
                w[i] = lo | (hi << 16);
            }
            long long g = ((long long)(bh * 64 + e)) * S_ + j * 256 + c * 64 + nb;
            uint4v* dst = (uint4v*)(vt + g);
            uint4v w0 = {w[0], w[1], w[2], w[3]};
            uint4v w1 = {w[4], w[5], w[6], w[7]};
            dst[0] = w0;
            dst[1] = w1;
        }
        __syncthreads();
    }

    float* o = kvt + ((long long)(bh * NB_ + j)) * 4096 + e * 64 + dg;
    *(f4*)(o + 0)  = acc[0];
    *(f4*)(o + 4)  = acc[1];
    *(f4*)(o + 8)  = acc[2];
    *(f4*)(o + 12) = acc[3];
}

// ---------------------------------------------------------------------------
// Phase 2: in-place prefix scan over block index j:
//   state entering block j:  S_j = bd*S_{j-1} + KVb_{j-1},  S_0 = 0
// Each thread owns fixed elements; read KVb_j, write S_j, update register state.
// ---------------------------------------------------------------------------
__global__ __launch_bounds__(256) void phase2_scan(float* __restrict__ kvt)
{
    const int bh = blockIdx.x;   // 0..127
    const int h  = bh & 63;
    const int t  = threadIdx.x;
    const float slope = slope_for_head(h);
    const float bd = __expf(-slope * 256.0f);

    const f32x4 zf = {0.f, 0.f, 0.f, 0.f};
    f4 st[4];
    st[0] = zf; st[1] = zf; st[2] = zf; st[3] = zf;

    f4* base = (f4*)(kvt + (long long)bh * NB_ * 4096);
    for (int j = 0; j < NB_; ++j) {
        f4* p = base + j * 1024;
        for (int i = 0; i < 4; ++i) {
            f4 tmp = p[t + i * 256];
            p[t + i * 256] = st[i];
            st[i] = st[i] * bd + tmp;
        }
    }
}

// ---------------------------------------------------------------------------
// Phase 3: per-(bh, block j), 4 independent waves each owning 64 m-rows.
// All MFMA 16x16x32 bf16. Computes O^T so fragments flow without transposes:
//   inter: O^T[e][m] += kvT[e][d] * q[m][d]      (then scale cols by q_decay[m])
//   S^T   = K @ Q^T (C frag: row=n, col=m)  -> decay -> P buffer [m][n] bf16
//   O^T  += V^T @ P^T  (A = vt from global, B = P rows, contiguous b128 reads)
// P is per-wave private LDS: NO barriers needed (waves have different trip counts).
// ---------------------------------------------------------------------------
__global__ __launch_bounds__(256, 2) void phase3_output(
    const float* __restrict__ q, const float* __restrict__ k,
    const float* __restrict__ kvt, const short* __restrict__ vt,
    float* __restrict__ out)
{
    __shared__ short P[4][64 * 56];   // per-wave [64 m][56 stride, 32 n used]
    const int j    = blockIdx.x;      // 0..15
    const int bh   = blockIdx.y;      // 0..127
    const int h    = bh & 63;
    const int tid  = threadIdx.x;
    const int wave = tid >> 6;
    const int lane = tid & 63;
    const int quad = lane >> 4;
    const int l16  = lane & 15;
    const int wrole  = (wave + j) & 3;   // balance causal trip counts across SIMDs
    const float slope = slope_for_head(h);
    const int mwbase = wrole << 6;       // wave's m base within the 256-block

    const long long rowbase = (long long)bh * S_ + j * 256 + mwbase;

    // ---- Q fragments (B-operand layout: B[k=ks*32+quad*8+jj][m=l16]) ----
    short8 qf[4][2];
    for (int mt = 0; mt < 4; ++mt) {
        const float* qp = q + (rowbase + mt * 16 + l16) * 64 + quad * 8;
        for (int ks = 0; ks < 2; ++ks) {
            f4 a = *(const f4*)(qp + ks * 32);
            f4 b = *(const f4*)(qp + ks * 32 + 4);
            short8 f;
            f[0] = f2bf(a.x); f[1] = f2bf(a.y); f[2] = f2bf(a.z); f[3] = f2bf(a.w);
            f[4] = f2bf(b.x); f[5] = f2bf(b.y); f[6] = f2bf(b.z); f[7] = f2bf(b.w);
            qf[mt][ks] = f;
        }
    }

    // ---- O^T accumulators: of[et][mt], C frag (row = e local, col = m local)
    const f32x4 zf = {0.f, 0.f, 0.f, 0.f};
    f32x4 of[4][4];
    for (int et = 0; et < 4; ++et)
        for (int mt = 0; mt < 4; ++mt) of[et][mt] = zf;

    // ---- inter-block: O^T += kvT @ Q^T ----
    const float* kvp = kvt + ((long long)(bh * NB_ + j) << 12);
    for (int et = 0; et < 4; ++et) {
        for (int ks = 0; ks < 2; ++ks) {
            const float* p = kvp + (et * 16 + l16) * 64 + ks * 32 + quad * 8;
            f4 a = *(const f4*)(p);
            f4 b = *(const f4*)(p + 4);
            short8 af;
            af[0] = f2bf(a.x); af[1] = f2bf(a.y); af[2] = f2bf(a.z); af[3] = f2bf(a.w);
            af[4] = f2bf(b.x); af[5] = f2bf(b.y); af[6] = f2bf(b.z); af[7] = f2bf(b.w);
            for (int mt = 0; mt < 4; ++mt)
                of[et][mt] = __builtin_amdgcn_mfma_f32_16x16x32_bf16(
                    af, qf[mt][ks], of[et][mt], 0, 0, 0);
        }
    }
    // scale columns (m) by q_decay[m] = exp(-slope*(m+1))
    for (int mt = 0; mt < 4; ++mt) {
        float qd = __expf(-slope * (float)(mwbase + mt * 16 + l16 + 1));
        for (int et = 0; et < 4; ++et) of[et][mt] *= qd;
    }

    // ---- intra-block, causal, chunks of 32 n ----
    const float er1 = __expf(slope);
    const float er2 = er1 * er1;
    const float er3 = er2 * er1;
    short* Pw = &P[wave][0];                 // index by PHYSICAL wave (privacy)
    const int nchunks = (mwbase >> 5) + 2;   // covers n < mwbase + 64

    for (int c = 0; c < nchunks; ++c) {
        const int nbase = c << 5;

        // K A-fragments (A[n=l16][k=ks*32+quad*8+jj])
        short8 kf[2][2];
        for (int nt = 0; nt < 2; ++nt) {
            const float* kp = k + ((long long)bh * S_ + j * 256 + nbase + nt * 16 + l16) * 64 + quad * 8;
            for (int ks = 0; ks < 2; ++ks) {
                f4 a = *(const f4*)(kp + ks * 32);
                f4 b = *(const f4*)(kp + ks * 32 + 4);
                short8 f;
                f[0] = f2bf(a.x); f[1] = f2bf(a.y); f[2] = f2bf(a.z); f[3] = f2bf(a.w);
                f[4] = f2bf(b.x); f[5] = f2bf(b.y); f[6] = f2bf(b.z); f[7] = f2bf(b.w);
                kf[nt][ks] = f;
            }
        }

        // S^T = K @ Q^T  (C frag: row = n local = quad*4+reg, col = m = l16)
        f32x4 sf[2][4];
        for (int nt = 0; nt < 2; ++nt)
            for (int mt = 0; mt < 4; ++mt) sf[nt][mt] = zf;
        for (int nt = 0; nt < 2; ++nt)
            for (int ks = 0; ks < 2; ++ks)
                for (int mt = 0; mt < 4; ++mt)
                    sf[nt][mt] = __builtin_amdgcn_mfma_f32_16x16x32_bf16(
                        kf[nt][ks], qf[mt][ks], sf[nt][mt], 0, 0, 0);

        // apply causal decay, cast bf16, store to per-wave P buffer [m][n]
        for (int nt = 0; nt < 2; ++nt) {
            for (int mt = 0; mt < 4; ++mt) {
                int n0 = nbase + nt * 16 + quad * 4;       // n at reg 0
                int m  = mwbase + mt * 16 + l16;
                float ddb = __expf(-slope * (float)(m - n0));
                f32x4 s = sf[nt][mt];
                float v0 = (m >= n0)     ? s[0] * ddb       : 0.f;
                float v1 = (m >= n0 + 1) ? s[1] * ddb * er1 : 0.f;
                float v2 = (m >= n0 + 2) ? s[2] * ddb * er2 : 0.f;
                float v3 = (m >= n0 + 3) ? s[3] * ddb * er3 : 0.f;
                short4v pk = {f2bf(v0), f2bf(v1), f2bf(v2), f2bf(v3)};
                *(short4v*)&Pw[(mt * 16 + l16) * 56 + nt * 16 + quad * 4] = pk;
            }
        }
        asm volatile("s_waitcnt lgkmcnt(0)" ::: "memory");

        // P B-fragments (B[k=n=quad*8+jj][m=l16]) — contiguous b128 reads
        short8 pb[4];
        for (int mt = 0; mt < 4; ++mt)
            pb[mt] = *(const short8*)&Pw[(mt * 16 + l16) * 56 + quad * 8];
        // V^T A-fragments straight from global bf16 (A[e=l16][n=quad*8+jj])
        short8 va[4];
        for (int et = 0; et < 4; ++et)
            va[et] = *(const short8*)(vt + ((long long)(bh * 64 + et * 16 + l16)) * S_
                                         + j * 256 + nbase + quad * 8);

        for (int et = 0; et < 4; ++et)
            for (int mt = 0; mt < 4; ++mt)
                of[et][mt] = __builtin_amdgcn_mfma_f32_16x16x32_bf16(
                    va[et], pb[mt], of[et][mt], 0, 0, 0);
    }

    // ---- epilogue: O^T frag (row=e, col=m) -> out[m][e], float4 stores ----
    for (int mt = 0; mt < 4; ++mt) {
        float* orow = out + (rowbase + mt * 16 + l16) * 64;
        for (int et = 0; et < 4; ++et) {
            f4 o = {of[et][mt][0], of[et][mt][1], of[et][mt][2], of[et][mt][3]};
            *(f4*)(orow + et * 16 + quad * 4) = o;
        }
    }
}

// ---------------------------------------------------------------------------
extern "C" void kernel_launch(void* const* d_in, const int* in_sizes, int n_in,
                              void* d_out, int out_size, void* d_ws, size_t ws_size,
                              hipStream_t stream) {
    const float* q    = (const float*)d_in[0];
    const float* k    = (const float*)d_in[1];
    const float* v    = (const float*)d_in[2];
    const int*   mask = (const int*)d_in[3];
    float* kvt = (float*)d_ws;                                   // 128*16*4096 f32 = 32 MB
    short* vt  = (short*)((char*)d_ws + (size_t)128 * 16 * 4096 * 4); // V^T bf16, 64 MB
    float* out = (float*)d_out;

    phase1_kvblocks<<<dim3(16, 128), 256, 0, stream>>>(k, v, mask, kvt, vt);
    phase2_scan<<<128, 256, 0, stream>>>(kvt);
    phase3_output<<<dim3(16, 128), 256, 0, stream>>>(q, k, kvt, vt, out);
}